// Round 4
// baseline (3594.501 us; speedup 1.0000x reference)
//
#include <hip/hip_runtime.h>
#include <math.h>

#define VOCAB 1000
#define EMB   128
#define HID   256
#define G4    1024   // 4*HID
#define BATCH 64
#define SEQT  1024
#define CHUNK 64     // hidden units per block
#define NBLK  4      // blocks per batch element
#define MAGIC 0x13572468

__device__ __forceinline__ float sigmoidf_(float x) {
    return 1.f / (1.f + __expf(-x));
}
__device__ __forceinline__ float tanhf_(float x) {
    return 1.f - 2.f / (__expf(2.f * x) + 1.f);
}

// sc0 = bypass L1, cacheable in the XCD's L2 (sc1=0). This is the fast
// same-XCD communication path; correctness never depends on it (dual-publish
// + bounded poll + agent-scope fallback below).
__device__ __forceinline__ void st_sc0(unsigned long long* p, unsigned long long v) {
    asm volatile("global_store_dwordx2 %0, %1, off sc0" :: "v"(p), "v"(v) : "memory");
}
__device__ __forceinline__ unsigned long long ld_sc0(const unsigned long long* p) {
    unsigned long long r;
    asm volatile("global_load_dwordx2 %0, %1, off sc0\n\t"
                 "s_waitcnt vmcnt(0)"
                 : "=&v"(r) : "v"(p) : "memory");
    return r;
}

// ---------------------------------------------------------------------------
// Kernel 1: eproj[v][g] = emb[v] . W_ih[g] + b_ih[g] + b_hh[g]   (131M MACs)
// ---------------------------------------------------------------------------
__global__ __launch_bounds__(1024) void eproj_kernel(
    const float* __restrict__ emb, const float* __restrict__ W_ih,
    const float* __restrict__ b_ih, const float* __restrict__ b_hh,
    float* __restrict__ eproj)
{
    const int v = blockIdx.x;
    const int g = threadIdx.x;
    __shared__ __align__(16) float x_sh[EMB];
    if (g < EMB / 4) {
        ((float4*)x_sh)[g] = ((const float4*)(emb + (size_t)v * EMB))[g];
    }
    __syncthreads();
    const float4* wrow = (const float4*)(W_ih + (size_t)g * EMB);
    float a0 = 0.f, a1 = 0.f, a2 = 0.f, a3 = 0.f;
#pragma unroll
    for (int e4 = 0; e4 < EMB / 4; e4++) {
        float4 wv = wrow[e4];
        float4 xv = ((const float4*)x_sh)[e4];
        a0 += wv.x * xv.x;
        a1 += wv.y * xv.y;
        a2 += wv.z * xv.z;
        a3 += wv.w * xv.w;
    }
    eproj[(size_t)v * G4 + g] = (a0 + a1) + (a2 + a3) + b_ih[g] + b_hh[g];
}

// ---------------------------------------------------------------------------
// Kernel 2: 4 blocks per batch element. Thread owns gate row r of W_hh in
// registers. Cross-block h exchange per step: packed (tag<<32|h) words,
// published BOTH via sc0 (same-XCD L2, fast) and agent scope (MALL, always
// correct). Consumers poll fast boundedly, then fall back to the agent copy;
// sticky demotion if the fast path never delivers (wrong XCD mapping).
// Startup: producers sc0-init their fast slots (kills stale L2 lines from a
// previous launch), then an agent-scope handshake gates the first fast poll.
// ---------------------------------------------------------------------------
template <bool FASTPATH>
__global__ __launch_bounds__(256, 1) void lstm_group_kernel(
    const int* __restrict__ ids, const int* __restrict__ lens,
    const float* __restrict__ eproj, const float* __restrict__ W_hh,
    unsigned long long* __restrict__ fastq,  // [2][BATCH][HID] packed (tag,h)
    unsigned long long* __restrict__ slowq,  // [2][BATCH][HID] packed (tag,h)
    int* __restrict__ initflag,              // [BATCH][NBLK]
    float* __restrict__ out)
{
    const int idx  = blockIdx.x;
    const int xcd  = idx & 7;
    const int m    = idx >> 3;
    const int s    = m & 3;          // chunk 0..3
    const int slot = m >> 2;         // 0..7
    const int b    = xcd + 8 * slot; // batch element; group's 4 blocks are
                                     // 8 apart -> same XCD under round-robin
    const int j  = threadIdx.x;      // 0..255
    const int gt = j >> 6;           // gate type 0..3 (i,f,g,o)
    const int ul = j & 63;           // unit-local 0..63
    const int r  = (gt << 8) | (s << 6) | ul;   // gate row 0..1023

    __shared__ __align__(16) float h_sh[HID];
    __shared__ __align__(16) float gates_sh[256];

    // W_hh row r -> registers (AGPR-backed on the unified file, no scratch)
    float w[HID];
    {
        const float4* wrow = (const float4*)(W_hh + (size_t)r * HID);
#pragma unroll
        for (int k4 = 0; k4 < HID / 4; k4++) {
            float4 wv = wrow[k4];
            w[4 * k4 + 0] = wv.x;
            w[4 * k4 + 1] = wv.y;
            w[4 * k4 + 2] = wv.z;
            w[4 * k4 + 3] = wv.w;
        }
    }

    const int len = lens[b];
    const int* ids_row = ids + (size_t)b * SEQT;

    h_sh[j] = 0.f;
    float c = 0.f;        // live in wave gt==s
    float hlast = 0.f;

    float xw = eproj[(size_t)ids_row[0] * G4 + r];

    unsigned long long* fast_b = fastq + (size_t)b * HID;
    unsigned long long* slow_b = slowq + (size_t)b * HID;
    const size_t par = (size_t)BATCH * HID;

    if constexpr (FASTPATH) {
        // init my fast produce-slots (both parities) so stale L2 lines from a
        // previous launch can never alias a valid tag, then agent handshake.
        if (gt == s) {
            st_sc0(&fast_b[(s << 6) | ul], 0ull);
            st_sc0(&fast_b[par + ((s << 6) | ul)], 0ull);
            asm volatile("s_waitcnt vmcnt(0)" ::: "memory");
        }
        __syncthreads();   // all waves' init stores are in L2
        if (j == 0) {
            __hip_atomic_store(&initflag[b * NBLK + s], MAGIC,
                               __ATOMIC_RELEASE, __HIP_MEMORY_SCOPE_AGENT);
        }
        if (j < NBLK && j != s) {
            while (__hip_atomic_load(&initflag[b * NBLK + j], __ATOMIC_ACQUIRE,
                                     __HIP_MEMORY_SCOPE_AGENT) != MAGIC) {
                __builtin_amdgcn_s_sleep(1);
            }
        }
    }
    __syncthreads();

    int fast_on   = FASTPATH ? 1 : 0;
    int fast_miss = 0;

    for (int step = 0; step < len; step++) {
        // prefetch next step's input projection (hides under the k-loop)
        const int nstep = (step + 1 < len) ? step + 1 : len - 1;
        const float xw_next = eproj[(size_t)ids_row[nstep] * G4 + r];

        // ---- gates: xw + w . h  (h broadcast float4 from LDS) ----
        float a0 = xw, a1 = 0.f, a2 = 0.f, a3 = 0.f;
#pragma unroll
        for (int k4 = 0; k4 < HID / 4; k4++) {
            float4 hv = ((const float4*)h_sh)[k4];
            a0 += w[4 * k4 + 0] * hv.x;
            a1 += w[4 * k4 + 1] * hv.y;
            a2 += w[4 * k4 + 2] * hv.z;
            a3 += w[4 * k4 + 3] * hv.w;
        }
        gates_sh[j] = (a0 + a1) + (a2 + a3);
        __syncthreads();

        const bool last = (step + 1 >= len);
        unsigned long long* fq = fast_b + (size_t)(step & 1) * par;
        unsigned long long* sq = slow_b + (size_t)(step & 1) * par;

        if (gt == s) {
            float ig = sigmoidf_(gates_sh[ul]);
            float fg = sigmoidf_(gates_sh[64 + ul]);
            float gg = tanhf_(gates_sh[128 + ul]);
            float og = sigmoidf_(gates_sh[192 + ul]);
            c = fg * c + ig * gg;
            float h = og * tanhf_(c);
            hlast = h;
            h_sh[(s << 6) | ul] = h;
            if (!last) {
                union { float f; unsigned u; } cv; cv.f = h;
                unsigned long long pk =
                    ((unsigned long long)(unsigned)(step + 1) << 32) | cv.u;
                if constexpr (FASTPATH) {
                    st_sc0(&fq[(s << 6) | ul], pk);   // fast copy first
                }
                __hip_atomic_store(&sq[(s << 6) | ul], pk,
                                   __ATOMIC_RELAXED, __HIP_MEMORY_SCOPE_AGENT);
            }
        } else if (!last) {
            const unsigned want = (unsigned)(step + 1);
            unsigned long long v = 0;
            bool have = false;
            if constexpr (FASTPATH) {
                if (fast_on) {
                    for (int it = 0; it < 10; ++it) {
                        if (!have) {
                            v = ld_sc0(&fq[(gt << 6) | ul]);
                            have = ((unsigned)(v >> 32) == want);
                        }
                        if (__all((int)have)) break;
                    }
                    if (!__all((int)have)) {
                        if (++fast_miss >= 3) fast_on = 0;  // sticky demotion
                    } else {
                        fast_miss = 0;
                    }
                }
            }
            while (!have) {      // guaranteed-correct agent-scope fallback
                v = __hip_atomic_load(&sq[(gt << 6) | ul],
                                      __ATOMIC_RELAXED, __HIP_MEMORY_SCOPE_AGENT);
                have = ((unsigned)(v >> 32) == want);
            }
            union { unsigned u; float f; } cv; cv.u = (unsigned)v;
            h_sh[(gt << 6) | ul] = cv.f;
        }
        __syncthreads();
        xw = xw_next;
    }

    if (gt == s) {
        out[(size_t)b * HID + ((s << 6) | ul)] = hlast;
    }
}

// ---------------------------------------------------------------------------
// Fallback (ws too small): correct-but-slow single-block version.
// ---------------------------------------------------------------------------
__global__ __launch_bounds__(1024, 1) void lstm_fallback(
    const int* __restrict__ ids, const int* __restrict__ lens,
    const float* __restrict__ emb, const float* __restrict__ W_ih,
    const float* __restrict__ b_ih, const float* __restrict__ b_hh,
    const float* __restrict__ W_hh, float* __restrict__ out)
{
    const int b = blockIdx.x;
    const int t = threadIdx.x;

    __shared__ __align__(16) float h_sh[HID];
    __shared__ __align__(16) float c_sh[HID];
    __shared__ __align__(16) float gates[G4];
    __shared__ __align__(16) float x_sh[EMB];

    float wih[EMB];
    {
        const float4* wr = (const float4*)(W_ih + (size_t)t * EMB);
#pragma unroll
        for (int e4 = 0; e4 < EMB / 4; e4++) {
            float4 wv = wr[e4];
            wih[4 * e4 + 0] = wv.x;
            wih[4 * e4 + 1] = wv.y;
            wih[4 * e4 + 2] = wv.z;
            wih[4 * e4 + 3] = wv.w;
        }
    }
    float bias = b_ih[t] + b_hh[t];

    const int len = lens[b];
    const int* ids_row = ids + (size_t)b * SEQT;
    if (t < HID) { h_sh[t] = 0.f; c_sh[t] = 0.f; }
    __syncthreads();

    for (int step = 0; step < len; step++) {
        int id = ids_row[step];
        if (t < EMB / 4) {
            ((float4*)x_sh)[t] = ((const float4*)(emb + (size_t)id * EMB))[t];
        }
        __syncthreads();
        float a0 = bias, a1 = 0.f, a2 = 0.f, a3 = 0.f;
#pragma unroll
        for (int e4 = 0; e4 < EMB / 4; e4++) {
            float4 xv = ((const float4*)x_sh)[e4];
            a0 += wih[4 * e4 + 0] * xv.x;
            a1 += wih[4 * e4 + 1] * xv.y;
            a2 += wih[4 * e4 + 2] * xv.z;
            a3 += wih[4 * e4 + 3] * xv.w;
        }
        float acc = (a0 + a1) + (a2 + a3);

        const float* wrow = W_hh + (size_t)t * HID;
        a0 = acc; a1 = 0.f; a2 = 0.f; a3 = 0.f;
        for (int k4 = 0; k4 < HID / 4; k4++) {
            float4 hv = ((const float4*)h_sh)[k4];
            float4 wv = ((const float4*)wrow)[k4];
            a0 += wv.x * hv.x;
            a1 += wv.y * hv.y;
            a2 += wv.z * hv.z;
            a3 += wv.w * hv.w;
        }
        gates[t] = (a0 + a1) + (a2 + a3);
        __syncthreads();

        if (t < HID) {
            float ig = sigmoidf_(gates[t]);
            float fg = sigmoidf_(gates[HID + t]);
            float gg = tanhf_(gates[2 * HID + t]);
            float og = sigmoidf_(gates[3 * HID + t]);
            float cc = fg * c_sh[t] + ig * gg;
            c_sh[t] = cc;
            h_sh[t] = og * tanhf_(cc);
        }
        __syncthreads();
    }
    if (t < HID) out[(size_t)b * HID + t] = h_sh[t];
}

extern "C" void kernel_launch(void* const* d_in, const int* in_sizes, int n_in,
                              void* d_out, int out_size, void* d_ws, size_t ws_size,
                              hipStream_t stream) {
    const int*   ids  = (const int*)d_in[0];
    const int*   lens = (const int*)d_in[1];
    const float* emb  = (const float*)d_in[2];
    const float* Wih  = (const float*)d_in[3];
    const float* Whh  = (const float*)d_in[4];
    const float* bih  = (const float*)d_in[5];
    const float* bhh  = (const float*)d_in[6];
    float* out = (float*)d_out;

    const size_t buf_bytes = (size_t)2 * BATCH * HID * sizeof(unsigned long long); // 256 KB
    const size_t ep_bytes  = (size_t)VOCAB * G4 * sizeof(float);                   // 4 MB

    // full layout: initflag(4KB) | fast(256KB) | slow(256KB) | eproj(4MB)
    const size_t fast_off = 4096;
    const size_t slow_off = fast_off + buf_bytes;
    const size_t ep_off_f = slow_off + buf_bytes;

    if (ws_size >= ep_off_f + ep_bytes) {
        int* initflag = (int*)d_ws;
        unsigned long long* fastq = (unsigned long long*)((char*)d_ws + fast_off);
        unsigned long long* slowq = (unsigned long long*)((char*)d_ws + slow_off);
        float* eproj = (float*)((char*)d_ws + ep_off_f);
        eproj_kernel<<<VOCAB, 1024, 0, stream>>>(emb, Wih, bih, bhh, eproj);
        lstm_group_kernel<true><<<BATCH * NBLK, 256, 0, stream>>>(
            ids, lens, eproj, Whh, fastq, slowq, initflag, out);
    } else if (ws_size >= buf_bytes + ep_bytes) {
        // no room for the fast region: round-3 style slow-only layout
        unsigned long long* slowq = (unsigned long long*)d_ws;
        float* eproj = (float*)((char*)d_ws + buf_bytes);
        eproj_kernel<<<VOCAB, 1024, 0, stream>>>(emb, Wih, bih, bhh, eproj);
        lstm_group_kernel<false><<<BATCH * NBLK, 256, 0, stream>>>(
            ids, lens, eproj, Whh, nullptr, slowq, nullptr, out);
    } else {
        lstm_fallback<<<BATCH, 1024, 0, stream>>>(
            ids, lens, emb, Wih, bih, bhh, Whh, out);
    }
}